// Round 10
// baseline (1497.942 us; speedup 1.0000x reference)
//
#include <hip/hip_runtime.h>

typedef float f32x4 __attribute__((ext_vector_type(4)));

#define B        32
#define C        256
#define CS       64
#define HW       3136
#define HW4      784
#define EPS      1e-5f
#define SPIN_CAP (1u << 22)

// One block per (b,c) plane. Single pass over x:
//   phase 1: plane -> LDS, pool, publish s[bc] (release) + count
//   phase 2: bounded spin until all 256 planes of batch b published
//   phase 3: gather s[b,:], redundant tiny MLP -> g for our channel
//   phase 4: out = LDS plane * g  (x never re-read)
__global__ __launch_bounds__(256) void se_onepass(
        const float* __restrict__ x,
        const float* __restrict__ w1,
        const float* __restrict__ bn1_gamma, const float* __restrict__ bn1_beta,
        const float* __restrict__ bn1_mean,  const float* __restrict__ bn1_var,
        const float* __restrict__ w2,
        const float* __restrict__ bn2_gamma, const float* __restrict__ bn2_beta,
        const float* __restrict__ bn2_mean,  const float* __restrict__ bn2_var,
        float* __restrict__ out,
        float* __restrict__ s,
        unsigned* __restrict__ cnt) {
    __shared__ f32x4 plane[HW4];      // 12544 B
    __shared__ float s_lds[C];
    __shared__ float h_lds[CS];
    __shared__ float red[4];
    __shared__ float gsh;
    __shared__ unsigned fbflag;

    const int bc   = blockIdx.x;      // 0..8191
    const int b    = bc >> 8;
    const int c    = bc & 255;
    const int t    = threadIdx.x;
    const int lane = t & 63;
    const int wid  = t >> 6;

    // ---- Phase 1: load plane into LDS, pool ----
    const f32x4* __restrict__ xp = (const f32x4*)x + (size_t)bc * HW4;
    float sum = 0.f;
    for (int i = t; i < HW4; i += 256) {
        f32x4 v = xp[i];
        plane[i] = v;
        sum += (v.x + v.y) + (v.z + v.w);
    }
    #pragma unroll
    for (int off = 32; off; off >>= 1) sum += __shfl_down(sum, off, 64);
    if (lane == 0) red[wid] = sum;
    __syncthreads();
    if (t == 0) {
        float tot = (red[0] + red[1]) + (red[2] + red[3]);
        __hip_atomic_store(&s[bc], tot * (1.0f / (float)HW),
                           __ATOMIC_RELAXED, __HIP_MEMORY_SCOPE_AGENT);
        __threadfence();               // release s[bc] before counting
        atomicAdd(&cnt[b], 1u);
        // ---- Phase 2: bounded spin until batch complete ----
        unsigned it = 0;
        while (__hip_atomic_load(&cnt[b], __ATOMIC_RELAXED,
                                 __HIP_MEMORY_SCOPE_AGENT) < (unsigned)C &&
               ++it < SPIN_CAP) {
            __builtin_amdgcn_s_sleep(4);
        }
        fbflag = (it >= SPIN_CAP) ? 1u : 0u;
    }
    __syncthreads();
    __threadfence();                   // acquire

    // ---- Phase 3: gather s[b,:] ----
    if (fbflag == 0u) {
        s_lds[t] = __hip_atomic_load(&s[b * C + t], __ATOMIC_RELAXED,
                                     __HIP_MEMORY_SCOPE_AGENT);
        __syncthreads();
    } else {
        // Escape hatch (pathological scheduling): recompute s[b,:] locally.
        for (int cc = 0; cc < C; ++cc) {
            const f32x4* pp = (const f32x4*)x + (size_t)(b * C + cc) * HW4;
            float ss = 0.f;
            for (int i = t; i < HW4; i += 256) {
                f32x4 v = pp[i];
                ss += (v.x + v.y) + (v.z + v.w);
            }
            #pragma unroll
            for (int off = 32; off; off >>= 1) ss += __shfl_down(ss, off, 64);
            if (lane == 0) red[wid] = ss;
            __syncthreads();
            if (t == 0)
                s_lds[cc] = ((red[0] + red[1]) + (red[2] + red[3])) * (1.0f / (float)HW);
            __syncthreads();
        }
    }

    // ---- MLP: h = ReLU(BN1(s @ w1^T)), 4 threads per output ----
    {
        const int cs = t >> 2, j = t & 3;
        const float4* wp = (const float4*)(w1 + cs * C) + j * 16;
        const float*  sp = s_lds + j * 64;
        float p = 0.f;
        #pragma unroll
        for (int k = 0; k < 16; ++k) {
            float4 w = wp[k];
            p += w.x * sp[4*k] + w.y * sp[4*k+1] + w.z * sp[4*k+2] + w.w * sp[4*k+3];
        }
        p += __shfl_xor(p, 1, 64);
        p += __shfl_xor(p, 2, 64);
        if (j == 0) {
            const float sc = bn1_gamma[cs] * rsqrtf(bn1_var[cs] + EPS);
            h_lds[cs] = fmaxf((p - bn1_mean[cs]) * sc + bn1_beta[cs], 0.f);
        }
    }
    __syncthreads();

    // ---- g for this block's channel c: threads 0..15 ----
    if (t < 16) {
        const float4 w = ((const float4*)(w2 + c * CS))[t];
        float a = w.x * h_lds[4*t] + w.y * h_lds[4*t+1]
                + w.z * h_lds[4*t+2] + w.w * h_lds[4*t+3];
        a += __shfl_xor(a, 1, 64);
        a += __shfl_xor(a, 2, 64);
        a += __shfl_xor(a, 4, 64);
        a += __shfl_xor(a, 8, 64);
        if (t == 0) {
            const float sc = bn2_gamma[c] * rsqrtf(bn2_var[c] + EPS);
            float gg = (a - bn2_mean[c]) * sc + bn2_beta[c];
            gsh = fminf(fmaxf(gg + 3.f, 0.f), 6.f) * (1.0f / 6.0f);
        }
    }
    __syncthreads();

    // ---- Phase 4: write out from LDS plane ----
    const float gv = gsh;
    f32x4* __restrict__ op = (f32x4*)out + (size_t)bc * HW4;
    for (int i = t; i < HW4; i += 256) {
        f32x4 v = plane[i];
        v.x *= gv; v.y *= gv; v.z *= gv; v.w *= gv;
        __builtin_nontemporal_store(v, op + i);
    }
}

extern "C" void kernel_launch(void* const* d_in, const int* in_sizes, int n_in,
                              void* d_out, int out_size, void* d_ws, size_t ws_size,
                              hipStream_t stream) {
    const float* x         = (const float*)d_in[0];
    const float* w1        = (const float*)d_in[1];
    const float* bn1_gamma = (const float*)d_in[2];
    const float* bn1_beta  = (const float*)d_in[3];
    const float* bn1_mean  = (const float*)d_in[4];
    const float* bn1_var   = (const float*)d_in[5];
    const float* w2        = (const float*)d_in[6];
    const float* bn2_gamma = (const float*)d_in[7];
    const float* bn2_beta  = (const float*)d_in[8];
    const float* bn2_mean  = (const float*)d_in[9];
    const float* bn2_var   = (const float*)d_in[10];
    float* out = (float*)d_out;

    float*    s   = (float*)d_ws;               // 8192 floats
    unsigned* cnt = (unsigned*)(s + B * C);     // 32 counters

    hipMemsetAsync(cnt, 0, B * sizeof(unsigned), stream);
    se_onepass<<<B * C, 256, 0, stream>>>(x, w1,
                                          bn1_gamma, bn1_beta, bn1_mean, bn1_var,
                                          w2,
                                          bn2_gamma, bn2_beta, bn2_mean, bn2_var,
                                          out, s, cnt);
}

// Round 11
// 59.627 us; speedup vs baseline: 25.1220x; 25.1220x over previous
//
#include <hip/hip_runtime.h>

typedef float f32x4 __attribute__((ext_vector_type(4)));

#define B    32
#define C    256
#define CS   64
#define HW   3136
#define HW4  784
#define EPS  1e-5f

// ---------------- Kernel 1: global average pool ----------------
// One block per (b,c) plane; nontemporal streaming reads (no reuse).
__global__ __launch_bounds__(256) void se_pool(const float* __restrict__ x,
                                               float* __restrict__ s) {
    const int bc = blockIdx.x;  // 0..8191
    const f32x4* __restrict__ xp = (const f32x4*)x + (size_t)bc * HW4;
    float sum = 0.f;
    for (int i = threadIdx.x; i < HW4; i += 256) {
        f32x4 v = __builtin_nontemporal_load(xp + i);
        sum += (v.x + v.y) + (v.z + v.w);
    }
    #pragma unroll
    for (int off = 32; off; off >>= 1) sum += __shfl_down(sum, off, 64);
    __shared__ float red[4];
    const int lane = threadIdx.x & 63;
    const int wid  = threadIdx.x >> 6;
    if (lane == 0) red[wid] = sum;
    __syncthreads();
    if (threadIdx.x == 0) {
        float t = (red[0] + red[1]) + (red[2] + red[3]);
        s[bc] = t * (1.0f / (float)HW);
    }
}

// ---------------- Kernel 2: whole MLP, one block per batch ----------------
__global__ __launch_bounds__(256) void se_mlp(
        const float* __restrict__ s,
        const float* __restrict__ w1,
        const float* __restrict__ bn1_gamma, const float* __restrict__ bn1_beta,
        const float* __restrict__ bn1_mean,  const float* __restrict__ bn1_var,
        const float* __restrict__ w2,
        const float* __restrict__ bn2_gamma, const float* __restrict__ bn2_beta,
        const float* __restrict__ bn2_mean,  const float* __restrict__ bn2_var,
        float* __restrict__ g) {
    __shared__ float s_lds[C];
    __shared__ float h_lds[CS];
    const int b = blockIdx.x;
    const int t = threadIdx.x;

    s_lds[t] = s[b * C + t];
    __syncthreads();

    // h[cs] = ReLU(BN1(dot(s, w1[cs,:]))) — 4 threads per output
    {
        const int cs = t >> 2, j = t & 3;
        const float4* wp = (const float4*)(w1 + cs * C) + j * 16;
        const float*  sp = s_lds + j * 64;
        float p = 0.f;
        #pragma unroll
        for (int k = 0; k < 16; ++k) {
            float4 w = wp[k];
            p += w.x * sp[4*k] + w.y * sp[4*k+1] + w.z * sp[4*k+2] + w.w * sp[4*k+3];
        }
        p += __shfl_xor(p, 1, 64);
        p += __shfl_xor(p, 2, 64);
        if (j == 0) {
            const float sc = bn1_gamma[cs] * rsqrtf(bn1_var[cs] + EPS);
            h_lds[cs] = fmaxf((p - bn1_mean[cs]) * sc + bn1_beta[cs], 0.f);
        }
    }
    __syncthreads();

    // g[c] = hsigmoid(BN2(dot(h, w2[c,:]))) — one thread per channel
    {
        const float4* wp = (const float4*)(w2 + t * CS);
        float a = 0.f;
        #pragma unroll
        for (int k = 0; k < 16; ++k) {
            float4 w = wp[k];
            a += w.x * h_lds[4*k] + w.y * h_lds[4*k+1]
               + w.z * h_lds[4*k+2] + w.w * h_lds[4*k+3];
        }
        const float sc = bn2_gamma[t] * rsqrtf(bn2_var[t] + EPS);
        float gg = (a - bn2_mean[t]) * sc + bn2_beta[t];
        g[b * C + t] = fminf(fmaxf(gg + 3.f, 0.f), 6.f) * (1.0f / 6.0f);
    }
}

// ---------------- Kernel 3: excite ----------------
// One block per (b,c) plane: wave-uniform g (scalar), no per-element div,
// nontemporal streaming load+store.
__global__ __launch_bounds__(256) void se_scale(const float* __restrict__ x,
                                                const float* __restrict__ g,
                                                float* __restrict__ out) {
    const int bc = blockIdx.x;  // 0..8191
    const float gv = g[bc];     // uniform -> s_load + broadcast
    const f32x4* __restrict__ xp = (const f32x4*)x + (size_t)bc * HW4;
    f32x4* __restrict__       op = (f32x4*)out + (size_t)bc * HW4;
    for (int i = threadIdx.x; i < HW4; i += 256) {
        f32x4 v = __builtin_nontemporal_load(xp + i);
        v.x *= gv; v.y *= gv; v.z *= gv; v.w *= gv;
        __builtin_nontemporal_store(v, op + i);
    }
}

extern "C" void kernel_launch(void* const* d_in, const int* in_sizes, int n_in,
                              void* d_out, int out_size, void* d_ws, size_t ws_size,
                              hipStream_t stream) {
    const float* x         = (const float*)d_in[0];
    const float* w1        = (const float*)d_in[1];
    const float* bn1_gamma = (const float*)d_in[2];
    const float* bn1_beta  = (const float*)d_in[3];
    const float* bn1_mean  = (const float*)d_in[4];
    const float* bn1_var   = (const float*)d_in[5];
    const float* w2        = (const float*)d_in[6];
    const float* bn2_gamma = (const float*)d_in[7];
    const float* bn2_beta  = (const float*)d_in[8];
    const float* bn2_mean  = (const float*)d_in[9];
    const float* bn2_var   = (const float*)d_in[10];
    float* out = (float*)d_out;

    float* s = (float*)d_ws;          // 8192 floats
    float* g = s + B * C;             // 8192 floats

    se_pool<<<B * C, 256, 0, stream>>>(x, s);
    se_mlp<<<B, 256, 0, stream>>>(s, w1, bn1_gamma, bn1_beta, bn1_mean, bn1_var,
                                  w2, bn2_gamma, bn2_beta, bn2_mean, bn2_var, g);
    se_scale<<<B * C, 256, 0, stream>>>(x, g, out);
}